// Round 6
// baseline (232.419 us; speedup 1.0000x reference)
//
#include <hip/hip_runtime.h>

// Self-attention (SAGAN-style), B=4, C=512, N=4096, O=64.
// Round 6:
//   pack_w:     weights -> bf16 frag "wall" (rt 0..3 f/g A-frags, 4..19 h B-frags).
//   proj_fused: reads x fp32 directly (no xb intermediate). Block = 640 rows x 64 n,
//               K=512 in chunks of 64 staged in LDS fp32; per-lane frag gathers
//               serve BOTH the f/g GEMM (x as B) and the h^T GEMM (x as A).
//   attn:       512 blocks (2/CU, 4 waves/SIMD), block = 64 m x 256 c.
//               Wave = 1 c-tile x 64 m. f staged via global_load_lds (double-buf),
//               h register-prefetched, E double-buffered, 1 barrier/iter.
// Fragment chunk convention (32-row tiles):
//   chunk[tile][q][lane][i] = M[idx = tile*32 + (lane&31)][k = q*16 + (lane>>5)*8 + i]

#define N_PIX 4096
#define C_IN  512

typedef __attribute__((ext_vector_type(8)))  short bf16x8;
typedef __attribute__((ext_vector_type(16))) float f32x16;

typedef __attribute__((address_space(1))) const unsigned int guint;
typedef __attribute__((address_space(3))) unsigned int luint;

__device__ __forceinline__ void gload_lds16(const void* g, void* l) {
    __builtin_amdgcn_global_load_lds((guint*)g, (luint*)l, 16, 0, 0);
}

__device__ inline unsigned int f2bf(float f) {
    union { float f; unsigned u; } x; x.f = f;
    unsigned r = x.u + 0x7FFFu + ((x.u >> 16) & 1u);
    return r >> 16;
}

__device__ __forceinline__ unsigned cvt_pk_bf16(float a, float b) {
#if __has_builtin(__builtin_amdgcn_cvt_pk_bf16_f32)
    auto r = __builtin_amdgcn_cvt_pk_bf16_f32(a, b);
    unsigned u; __builtin_memcpy(&u, &r, 4); return u;
#else
    return f2bf(a) | (f2bf(b) << 16);
#endif
}

// ---------------------------------------------------------------------------
// pack_w: 40960 octets into the contiguous wall: [0,8192) f/g A-frags (rt 0..3),
// [8192,40960) h B-frags (rt 4..19). grid 160, block 256.
__global__ __launch_bounds__(256) void pack_w(
    const float* __restrict__ f_w, const float* __restrict__ g_w,
    const float* __restrict__ h_w,
    unsigned short* __restrict__ wfg, unsigned short* __restrict__ whb)
{
    const int idx = blockIdx.x * 256 + threadIdx.x;
    const float* W;
    unsigned short* dst;
    int sub;
    if (idx < 8192) {
        const int ot = idx >> 11, rem = idx & 2047;
        const int q = rem >> 6, l = rem & 63;
        const int o = ot * 32 + (l & 31);
        W = (o < 64) ? &f_w[(size_t)o * C_IN] : &g_w[(size_t)(o - 64) * C_IN];
        dst = wfg; sub = idx;
        W += q * 16 + (l >> 5) * 8;
    } else {
        const int id2 = idx - 8192;
        const int ct = id2 >> 11, rem = id2 & 2047;
        const int q = rem >> 6, l = rem & 63;
        const int co = ct * 32 + (l & 31);
        W = &h_w[(size_t)co * C_IN + q * 16 + (l >> 5) * 8];
        dst = whb; sub = id2;
    }
    float4 v0 = *(const float4*)(W);
    float4 v1 = *(const float4*)(W + 4);
    uint4 pk;
    pk.x = cvt_pk_bf16(v0.x, v0.y);
    pk.y = cvt_pk_bf16(v0.z, v0.w);
    pk.z = cvt_pk_bf16(v1.x, v1.y);
    pk.w = cvt_pk_bf16(v1.z, v1.w);
    *(uint4*)&dst[(size_t)sub * 8] = pk;
}

// ---------------------------------------------------------------------------
// proj_fused: grid (64 n-blocks, B), block 512 (8 waves).
// Wave w: nsub = w&1 (32-n subtile), rg = w>>1; row-tiles rt = rg*5 + 0..4.
__global__ __launch_bounds__(512, 2) void proj_fused(
    const float* __restrict__ x,
    const unsigned short* __restrict__ wall,
    const float* __restrict__ f_b, const float* __restrict__ g_b,
    const float* __restrict__ h_b,
    unsigned short* __restrict__ fa, unsigned short* __restrict__ gbuf,
    unsigned short* __restrict__ ha)
{
    __shared__ __align__(16) float Xs[64 * 68];   // [c][n], row 68 (pad 4)
    const int t    = threadIdx.x;
    const int w    = t >> 6;
    const int l    = t & 63;
    const int lane = l & 31;
    const int half = l >> 5;
    const int nsub = w & 1;
    const int rg   = w >> 1;
    const int bx = blockIdx.x, b = blockIdx.y;
    const int n0 = bx * 64;

    f32x16 acc[5];
    #pragma unroll
    for (int j = 0; j < 5; ++j)
        #pragma unroll
        for (int r = 0; r < 16; ++r) acc[j][r] = 0.f;

    // preload + stage chunk 0
    {
        float4 xpre[2];
        #pragma unroll
        for (int k = 0; k < 2; ++k) {
            const int e = t + k * 512;
            const int c = e >> 4, n = (e & 15) * 4;
            xpre[k] = *(const float4*)&x[((size_t)(b * C_IN + c)) * N_PIX + n0 + n];
        }
        #pragma unroll
        for (int k = 0; k < 2; ++k) {
            const int e = t + k * 512;
            const int c = e >> 4, n = (e & 15) * 4;
            *(float4*)&Xs[c * 68 + n] = xpre[k];
        }
    }
    __syncthreads();

    const unsigned short* wp = wall + (size_t)l * 8;
    for (int it = 0; it < 8; ++it) {
        float4 xnext[2];
        if (it < 7) {
            #pragma unroll
            for (int k = 0; k < 2; ++k) {
                const int e = t + k * 512;
                const int c = e >> 4, n = (e & 15) * 4;
                xnext[k] = *(const float4*)&x[((size_t)(b * C_IN + (it + 1) * 64 + c)) * N_PIX + n0 + n];
            }
        }
        #pragma unroll
        for (int q = 0; q < 4; ++q) {
            // gather this wave's x fragment (c-octet q*16+half*8, n = nsub*32+lane)
            float xs[8];
            const int crow = q * 16 + half * 8;
            const int nloc = nsub * 32 + lane;
            #pragma unroll
            for (int i = 0; i < 8; ++i) xs[i] = Xs[(crow + i) * 68 + nloc];
            union { unsigned u[4]; bf16x8 v; } xf;
            xf.u[0] = cvt_pk_bf16(xs[0], xs[1]);
            xf.u[1] = cvt_pk_bf16(xs[2], xs[3]);
            xf.u[2] = cvt_pk_bf16(xs[4], xs[5]);
            xf.u[3] = cvt_pk_bf16(xs[6], xs[7]);
            const int qg = it * 4 + q;
            #pragma unroll
            for (int j = 0; j < 5; ++j) {
                const int rt = rg * 5 + j;
                bf16x8 wf = *(const bf16x8*)(wp + (size_t)rt * 16384 + (size_t)qg * 512);
                if (rt < 4)   // f/g: D[o][n] = W x
                    acc[j] = __builtin_amdgcn_mfma_f32_32x32x16_bf16(wf, xf.v, acc[j], 0, 0, 0);
                else          // h^T: D[n][c] = x^T W^T
                    acc[j] = __builtin_amdgcn_mfma_f32_32x32x16_bf16(xf.v, wf, acc[j], 0, 0, 0);
            }
        }
        __syncthreads();
        if (it < 7) {
            #pragma unroll
            for (int k = 0; k < 2; ++k) {
                const int e = t + k * 512;
                const int c = e >> 4, n = (e & 15) * 4;
                *(float4*)&Xs[c * 68 + n] = xnext[k];
            }
        }
        __syncthreads();
    }

    // epilogue
    const int ntile = bx * 2 + nsub;
    #pragma unroll
    for (int j = 0; j < 5; ++j) {
        const int rt = rg * 5 + j;
        if (rt < 4) {
            unsigned short* buf = (rt < 2) ? fa : gbuf;
            const float* bias = (rt < 2) ? f_b : g_b;
            #pragma unroll
            for (int j2 = 0; j2 < 4; ++j2) {
                const int o_base = (rt & 1) * 32 + 8 * j2 + 4 * half;
                float4 bv = *(const float4*)&bias[o_base];
                const int q  = o_base >> 4;
                const int lp = (l & 31) + 32 * (j2 & 1);
                uint2 pk;
                pk.x = cvt_pk_bf16(acc[j][4 * j2 + 0] + bv.x, acc[j][4 * j2 + 1] + bv.y);
                pk.y = cvt_pk_bf16(acc[j][4 * j2 + 2] + bv.z, acc[j][4 * j2 + 3] + bv.w);
                size_t off = (((size_t)(b * 128 + ntile) * 4 + q) * 64 + lp) * 8 + 4 * half;
                *(uint2*)&buf[off] = pk;
            }
        } else {
            const int ctile = rt - 4;
            const float hb = h_b[ctile * 32 + (l & 31)];
            #pragma unroll
            for (int j2 = 0; j2 < 4; ++j2) {
                const int q  = ntile * 2 + (j2 >> 1);
                const int lp = (l & 31) + 32 * (j2 & 1);
                uint2 pk;
                pk.x = cvt_pk_bf16(acc[j][4 * j2 + 0] + hb, acc[j][4 * j2 + 1] + hb);
                pk.y = cvt_pk_bf16(acc[j][4 * j2 + 2] + hb, acc[j][4 * j2 + 3] + hb);
                size_t off = (((size_t)(b * 16 + ctile) * 256 + q) * 64 + lp) * 8 + 4 * half;
                *(uint2*)&ha[off] = pk;
            }
        }
    }
}

// ---------------------------------------------------------------------------
// attn: grid 512 (2 blocks/CU), block 512 (8 waves). Block = 64 m x 256 c.
// Wave w: S-tile (nsub=w&3, mt=w>>2); PV c-tile cw=w.
__global__ __launch_bounds__(512, 4) void attn_kernel(
    const unsigned short* __restrict__ fa,
    const unsigned short* __restrict__ gbuf,
    const unsigned short* __restrict__ ha,
    const float* __restrict__ x,
    const float* __restrict__ gamma_p,
    float* __restrict__ out)
{
    __shared__ unsigned short Ebuf[2][64 * 136];          // 34.8 KB
    __shared__ __align__(16) unsigned short Fst[2][16 * 512]; // 32 KB f staging
    __shared__ float den_part[4][64];
    __shared__ float den_inv[64];

    const int t    = threadIdx.x;
    const int w    = t >> 6;
    const int l    = t & 63;
    const int lane = l & 31;
    const int half = l >> 5;
    const int nsub = w & 3;   // S n-subtile
    const int mt   = w >> 2;  // S m-tile (0..1)

    // blk%8 fixes (chalf, b) per XCD -> per-XCD h slice 2 MB, L2-resident
    const int blk   = blockIdx.x;
    const int chalf = blk & 1;
    const int b     = (blk >> 1) & 3;
    const int mi    = blk >> 3;       // 0..63
    const int m0    = mi * 64;

    // persistent g fragments for S m-tile (mi*2 + mt)
    bf16x8 gfrag[4];
    {
        const unsigned short* gp = gbuf
            + ((size_t)(b * 128 + mi * 2 + mt) * 4) * 512 + (size_t)l * 8;
        #pragma unroll
        for (int q = 0; q < 4; ++q)
            gfrag[q] = *(const bf16x8*)(gp + (size_t)q * 512);
    }

    f32x16 acc[2];   // [m-tile 0,1] for this wave's c-tile
    #pragma unroll
    for (int j = 0; j < 2; ++j)
        #pragma unroll
        for (int r = 0; r < 16; ++r) acc[j][r] = 0.f;

    float denp = 0.f;

    const unsigned short* fbase = fa + (size_t)b * (128 * 4) * 512;
    const int ctg = chalf * 8 + w;   // this wave's global 32-c tile
    const unsigned short* hbase = ha + ((size_t)(b * 16 + ctg)) * 256 * 512 + (size_t)l * 8;

    // stage f(0): wave stages chunks 2w, 2w+1
    #pragma unroll
    for (int j = 0; j < 2; ++j) {
        const int chunk = w * 2 + j;
        const unsigned short* src = fbase
            + ((size_t)((chunk >> 2)) * 4 + (chunk & 3)) * 512 + (size_t)l * 8;
        gload_lds16(src, &Fst[0][chunk * 512]);
    }
    __syncthreads();

    for (int nt = 0; nt < 32; ++nt) {
        // stage f(nt+1)
        if (nt < 31) {
            #pragma unroll
            for (int j = 0; j < 2; ++j) {
                const int chunk = w * 2 + j;
                const unsigned short* src = fbase
                    + ((size_t)((nt + 1) * 4 + (chunk >> 2)) * 4 + (chunk & 3)) * 512
                    + (size_t)l * 8;
                gload_lds16(src, &Fst[(nt + 1) & 1][chunk * 512]);
            }
        }
        // ---- S phase: one 32x32 tile (nsub, mt) ----
        bf16x8 ff[4];
        #pragma unroll
        for (int q = 0; q < 4; ++q)
            ff[q] = *(const bf16x8*)&Fst[nt & 1][(nsub * 4 + q) * 512 + l * 8];
        f32x16 s;
        #pragma unroll
        for (int r = 0; r < 16; ++r) s[r] = 0.f;
        #pragma unroll
        for (int q = 0; q < 4; ++q)
            s = __builtin_amdgcn_mfma_f32_32x32x16_bf16(ff[q], gfrag[q], s, 0, 0, 0);
        unsigned short* ew = &Ebuf[nt & 1][(mt * 32 + lane) * 136 + nsub * 32 + half * 4];
        #pragma unroll
        for (int r4 = 0; r4 < 4; ++r4) {
            float e0 = __expf(s[r4 * 4 + 0]);
            float e1 = __expf(s[r4 * 4 + 1]);
            float e2 = __expf(s[r4 * 4 + 2]);
            float e3 = __expf(s[r4 * 4 + 3]);
            denp += (e0 + e1) + (e2 + e3);
            uint2 pk;
            pk.x = cvt_pk_bf16(e0, e1);
            pk.y = cvt_pk_bf16(e2, e3);
            *(uint2*)(ew + r4 * 8) = pk;
        }
        // ---- h prefetch (independent of E) ----
        bf16x8 hreg[8];
        {
            const unsigned short* hp = hbase + (size_t)(nt * 8) * 512;
            #pragma unroll
            for (int q = 0; q < 8; ++q)
                hreg[q] = *(const bf16x8*)(hp + (size_t)q * 512);
        }
        __syncthreads();
        // ---- PV phase: 1 c-tile x 64 m ----
        const unsigned short* eb = &Ebuf[nt & 1][0];
        #pragma unroll
        for (int q = 0; q < 8; ++q) {
            bf16x8 b0 = *(const bf16x8*)(eb + lane * 136 + q * 16 + half * 8);
            bf16x8 b1 = *(const bf16x8*)(eb + (32 + lane) * 136 + q * 16 + half * 8);
            acc[0] = __builtin_amdgcn_mfma_f32_32x32x16_bf16(hreg[q], b0, acc[0], 0, 0, 0);
            acc[1] = __builtin_amdgcn_mfma_f32_32x32x16_bf16(hreg[q], b1, acc[1], 0, 0, 0);
        }
        // single barrier per iter: E and Fst double-buffered.
    }

    // ---- denominator reduction ----
    denp += __shfl_xor(denp, 32, 64);
    if (l < 32) den_part[nsub][mt * 32 + lane] = denp;
    __syncthreads();
    if (t < 64) {
        float d = den_part[0][t] + den_part[1][t] + den_part[2][t] + den_part[3][t];
        den_inv[t] = 1.0f / d;
    }
    __syncthreads();

    // ---- epilogue ----
    const float gs = gamma_p[0];
    #pragma unroll
    for (int mt2 = 0; mt2 < 2; ++mt2) {
        const int mloc = mt2 * 32 + lane;
        const float dinv = den_inv[mloc];
        const int m = m0 + mloc;
        #pragma unroll
        for (int r = 0; r < 16; ++r) {
            const int c = ctg * 32 + (r & 3) + ((r >> 2) * 8) + half * 4;
            const size_t idx = ((size_t)(b * C_IN + c)) * N_PIX + m;
            out[idx] = gs * acc[mt2][r] * dinv + x[idx];
        }
    }
}

// ---------------------------------------------------------------------------
extern "C" void kernel_launch(void* const* d_in, const int* in_sizes, int n_in,
                              void* d_out, int out_size, void* d_ws, size_t ws_size,
                              hipStream_t stream)
{
    const float* x     = (const float*)d_in[0];
    const float* f_w   = (const float*)d_in[1];
    const float* f_b   = (const float*)d_in[2];
    const float* g_w   = (const float*)d_in[3];
    const float* g_b   = (const float*)d_in[4];
    const float* h_w   = (const float*)d_in[5];
    const float* h_b   = (const float*)d_in[6];
    const float* gamma = (const float*)d_in[7];
    float* out = (float*)d_out;

    unsigned short* fa   = (unsigned short*)d_ws;        // 1M shorts (2 MB)
    unsigned short* gbuf = fa + (1u << 20);              // 1M shorts
    unsigned short* ha   = gbuf + (1u << 20);            // 8M shorts (16 MB)
    unsigned short* wfg  = ha + (8u << 20);              // 64K shorts
    unsigned short* whb  = wfg + (1u << 16);             // 256K shorts (contiguous wall)

    pack_w<<<160, 256, 0, stream>>>(f_w, g_w, h_w, wfg, whb);

    dim3 gp(64, 4);
    proj_fused<<<gp, 512, 0, stream>>>(x, wfg, f_b, g_b, h_b, fa, gbuf, ha);

    attn_kernel<<<512, 512, 0, stream>>>(fa, gbuf, ha, x, gamma, out);
}

// Round 7
// 217.936 us; speedup vs baseline: 1.0665x; 1.0665x over previous
//
#include <hip/hip_runtime.h>

// Self-attention (SAGAN-style), B=4, C=512, N=4096, O=64.
// Round 7:
//   proj_fused: software-pipelined — all 4 x-fragments gathered right after the
//               barrier (latencies overlap), weight fragments register-prefetched
//               one q-step ahead (incl. across iterations). Removes the
//               global-load->MFMA direct dependency that made r6 latency-bound.
//   pack_w / attn: unchanged from round 6.
// Fragment chunk convention (32-row tiles):
//   chunk[tile][q][lane][i] = M[idx = tile*32 + (lane&31)][k = q*16 + (lane>>5)*8 + i]

#define N_PIX 4096
#define C_IN  512

typedef __attribute__((ext_vector_type(8)))  short bf16x8;
typedef __attribute__((ext_vector_type(16))) float f32x16;

typedef __attribute__((address_space(1))) const unsigned int guint;
typedef __attribute__((address_space(3))) unsigned int luint;

__device__ __forceinline__ void gload_lds16(const void* g, void* l) {
    __builtin_amdgcn_global_load_lds((guint*)g, (luint*)l, 16, 0, 0);
}

__device__ inline unsigned int f2bf(float f) {
    union { float f; unsigned u; } x; x.f = f;
    unsigned r = x.u + 0x7FFFu + ((x.u >> 16) & 1u);
    return r >> 16;
}

__device__ __forceinline__ unsigned cvt_pk_bf16(float a, float b) {
#if __has_builtin(__builtin_amdgcn_cvt_pk_bf16_f32)
    auto r = __builtin_amdgcn_cvt_pk_bf16_f32(a, b);
    unsigned u; __builtin_memcpy(&u, &r, 4); return u;
#else
    return f2bf(a) | (f2bf(b) << 16);
#endif
}

// ---------------------------------------------------------------------------
// pack_w: 40960 octets into the contiguous wall: [0,8192) f/g A-frags (rt 0..3),
// [8192,40960) h B-frags (rt 4..19). grid 160, block 256.
__global__ __launch_bounds__(256) void pack_w(
    const float* __restrict__ f_w, const float* __restrict__ g_w,
    const float* __restrict__ h_w,
    unsigned short* __restrict__ wfg, unsigned short* __restrict__ whb)
{
    const int idx = blockIdx.x * 256 + threadIdx.x;
    const float* W;
    unsigned short* dst;
    int sub;
    if (idx < 8192) {
        const int ot = idx >> 11, rem = idx & 2047;
        const int q = rem >> 6, l = rem & 63;
        const int o = ot * 32 + (l & 31);
        W = (o < 64) ? &f_w[(size_t)o * C_IN] : &g_w[(size_t)(o - 64) * C_IN];
        dst = wfg; sub = idx;
        W += q * 16 + (l >> 5) * 8;
    } else {
        const int id2 = idx - 8192;
        const int ct = id2 >> 11, rem = id2 & 2047;
        const int q = rem >> 6, l = rem & 63;
        const int co = ct * 32 + (l & 31);
        W = &h_w[(size_t)co * C_IN + q * 16 + (l >> 5) * 8];
        dst = whb; sub = id2;
    }
    float4 v0 = *(const float4*)(W);
    float4 v1 = *(const float4*)(W + 4);
    uint4 pk;
    pk.x = cvt_pk_bf16(v0.x, v0.y);
    pk.y = cvt_pk_bf16(v0.z, v0.w);
    pk.z = cvt_pk_bf16(v1.x, v1.y);
    pk.w = cvt_pk_bf16(v1.z, v1.w);
    *(uint4*)&dst[(size_t)sub * 8] = pk;
}

// ---------------------------------------------------------------------------
// proj_fused: grid (64 n-blocks, B), block 512 (8 waves).
// Wave w: nsub = w&1 (32-n subtile), rg = w>>1; row-tiles rt = rg*5 + 0..4.
// Pipelined: x-frags gathered in a batch; weights prefetched one q-step ahead.
__global__ __launch_bounds__(512, 2) void proj_fused(
    const float* __restrict__ x,
    const unsigned short* __restrict__ wall,
    const float* __restrict__ f_b, const float* __restrict__ g_b,
    const float* __restrict__ h_b,
    unsigned short* __restrict__ fa, unsigned short* __restrict__ gbuf,
    unsigned short* __restrict__ ha)
{
    __shared__ __align__(16) float Xs[64 * 68];   // [c][n], row 68 (pad 4)
    const int t    = threadIdx.x;
    const int w    = t >> 6;
    const int l    = t & 63;
    const int lane = l & 31;
    const int half = l >> 5;
    const int nsub = w & 1;
    const int rg   = w >> 1;
    const int bx = blockIdx.x, b = blockIdx.y;
    const int n0 = bx * 64;

    f32x16 acc[5];
    #pragma unroll
    for (int j = 0; j < 5; ++j)
        #pragma unroll
        for (int r = 0; r < 16; ++r) acc[j][r] = 0.f;

    // preload + stage chunk 0
    {
        float4 xpre[2];
        #pragma unroll
        for (int k = 0; k < 2; ++k) {
            const int e = t + k * 512;
            const int c = e >> 4, n = (e & 15) * 4;
            xpre[k] = *(const float4*)&x[((size_t)(b * C_IN + c)) * N_PIX + n0 + n];
        }
        #pragma unroll
        for (int k = 0; k < 2; ++k) {
            const int e = t + k * 512;
            const int c = e >> 4, n = (e & 15) * 4;
            *(float4*)&Xs[c * 68 + n] = xpre[k];
        }
    }
    __syncthreads();

    const unsigned short* wp = wall + (size_t)(rg * 5) * 16384 + (size_t)l * 8;
    const int nloc = nsub * 32 + lane;

    // prime the weight pipeline: qg = 0
    bf16x8 wc[5];
    #pragma unroll
    for (int j = 0; j < 5; ++j)
        wc[j] = *(const bf16x8*)(wp + (size_t)j * 16384);

    for (int it = 0; it < 8; ++it) {
        // preload next x chunk (regs; independent of LDS)
        float4 xnext[2];
        if (it < 7) {
            #pragma unroll
            for (int k = 0; k < 2; ++k) {
                const int e = t + k * 512;
                const int c = e >> 4, n = (e & 15) * 4;
                xnext[k] = *(const float4*)&x[((size_t)(b * C_IN + (it + 1) * 64 + c)) * N_PIX + n0 + n];
            }
        }
        // gather all 4 x fragments for this K-chunk (32 LDS reads, batched)
        bf16x8 xf[4];
        #pragma unroll
        for (int q = 0; q < 4; ++q) {
            float xs[8];
            const int crow = q * 16 + half * 8;
            #pragma unroll
            for (int i = 0; i < 8; ++i) xs[i] = Xs[(crow + i) * 68 + nloc];
            union { unsigned u[4]; bf16x8 v; } c;
            c.u[0] = cvt_pk_bf16(xs[0], xs[1]);
            c.u[1] = cvt_pk_bf16(xs[2], xs[3]);
            c.u[2] = cvt_pk_bf16(xs[4], xs[5]);
            c.u[3] = cvt_pk_bf16(xs[6], xs[7]);
            xf[q] = c.v;
        }
        // MFMA with one-q-step-ahead weight prefetch
        #pragma unroll
        for (int q = 0; q < 4; ++q) {
            const int qg = it * 4 + q;
            bf16x8 wn[5];
            const int qn = (qg + 1) & 31;   // next qg (wraps harmlessly at end)
            #pragma unroll
            for (int j = 0; j < 5; ++j)
                wn[j] = *(const bf16x8*)(wp + (size_t)j * 16384 + (size_t)qn * 512);
            #pragma unroll
            for (int j = 0; j < 5; ++j) {
                const int rt = rg * 5 + j;
                if (rt < 4)   // f/g: D[o][n] = W x
                    acc[j] = __builtin_amdgcn_mfma_f32_32x32x16_bf16(wc[j], xf[q], acc[j], 0, 0, 0);
                else          // h^T: D[n][c] = x^T W^T
                    acc[j] = __builtin_amdgcn_mfma_f32_32x32x16_bf16(xf[q], wc[j], acc[j], 0, 0, 0);
            }
            #pragma unroll
            for (int j = 0; j < 5; ++j) wc[j] = wn[j];
        }
        __syncthreads();
        if (it < 7) {
            #pragma unroll
            for (int k = 0; k < 2; ++k) {
                const int e = t + k * 512;
                const int c = e >> 4, n = (e & 15) * 4;
                *(float4*)&Xs[c * 68 + n] = xnext[k];
            }
        }
        __syncthreads();
    }

    // epilogue
    const int ntile = bx * 2 + nsub;
    #pragma unroll
    for (int j = 0; j < 5; ++j) {
        const int rt = rg * 5 + j;
        if (rt < 4) {
            unsigned short* buf = (rt < 2) ? fa : gbuf;
            const float* bias = (rt < 2) ? f_b : g_b;
            #pragma unroll
            for (int j2 = 0; j2 < 4; ++j2) {
                const int o_base = (rt & 1) * 32 + 8 * j2 + 4 * half;
                float4 bv = *(const float4*)&bias[o_base];
                const int q  = o_base >> 4;
                const int lp = (l & 31) + 32 * (j2 & 1);
                uint2 pk;
                pk.x = cvt_pk_bf16(acc[j][4 * j2 + 0] + bv.x, acc[j][4 * j2 + 1] + bv.y);
                pk.y = cvt_pk_bf16(acc[j][4 * j2 + 2] + bv.z, acc[j][4 * j2 + 3] + bv.w);
                size_t off = (((size_t)(b * 128 + ntile) * 4 + q) * 64 + lp) * 8 + 4 * half;
                *(uint2*)&buf[off] = pk;
            }
        } else {
            const int ctile = rt - 4;
            const float hb = h_b[ctile * 32 + (l & 31)];
            #pragma unroll
            for (int j2 = 0; j2 < 4; ++j2) {
                const int q  = ntile * 2 + (j2 >> 1);
                const int lp = (l & 31) + 32 * (j2 & 1);
                uint2 pk;
                pk.x = cvt_pk_bf16(acc[j][4 * j2 + 0] + hb, acc[j][4 * j2 + 1] + hb);
                pk.y = cvt_pk_bf16(acc[j][4 * j2 + 2] + hb, acc[j][4 * j2 + 3] + hb);
                size_t off = (((size_t)(b * 16 + ctile) * 256 + q) * 64 + lp) * 8 + 4 * half;
                *(uint2*)&ha[off] = pk;
            }
        }
    }
}

// ---------------------------------------------------------------------------
// attn: grid 512 (2 blocks/CU), block 512 (8 waves). Block = 64 m x 256 c.
// Wave w: S-tile (nsub=w&3, mt=w>>2); PV c-tile cw=w. Unchanged from round 6.
__global__ __launch_bounds__(512, 4) void attn_kernel(
    const unsigned short* __restrict__ fa,
    const unsigned short* __restrict__ gbuf,
    const unsigned short* __restrict__ ha,
    const float* __restrict__ x,
    const float* __restrict__ gamma_p,
    float* __restrict__ out)
{
    __shared__ unsigned short Ebuf[2][64 * 136];          // 34.8 KB
    __shared__ __align__(16) unsigned short Fst[2][16 * 512]; // 32 KB f staging
    __shared__ float den_part[4][64];
    __shared__ float den_inv[64];

    const int t    = threadIdx.x;
    const int w    = t >> 6;
    const int l    = t & 63;
    const int lane = l & 31;
    const int half = l >> 5;
    const int nsub = w & 3;   // S n-subtile
    const int mt   = w >> 2;  // S m-tile (0..1)

    const int blk   = blockIdx.x;
    const int chalf = blk & 1;
    const int b     = (blk >> 1) & 3;
    const int mi    = blk >> 3;       // 0..63
    const int m0    = mi * 64;

    bf16x8 gfrag[4];
    {
        const unsigned short* gp = gbuf
            + ((size_t)(b * 128 + mi * 2 + mt) * 4) * 512 + (size_t)l * 8;
        #pragma unroll
        for (int q = 0; q < 4; ++q)
            gfrag[q] = *(const bf16x8*)(gp + (size_t)q * 512);
    }

    f32x16 acc[2];
    #pragma unroll
    for (int j = 0; j < 2; ++j)
        #pragma unroll
        for (int r = 0; r < 16; ++r) acc[j][r] = 0.f;

    float denp = 0.f;

    const unsigned short* fbase = fa + (size_t)b * (128 * 4) * 512;
    const int ctg = chalf * 8 + w;
    const unsigned short* hbase = ha + ((size_t)(b * 16 + ctg)) * 256 * 512 + (size_t)l * 8;

    #pragma unroll
    for (int j = 0; j < 2; ++j) {
        const int chunk = w * 2 + j;
        const unsigned short* src = fbase
            + ((size_t)((chunk >> 2)) * 4 + (chunk & 3)) * 512 + (size_t)l * 8;
        gload_lds16(src, &Fst[0][chunk * 512]);
    }
    __syncthreads();

    for (int nt = 0; nt < 32; ++nt) {
        if (nt < 31) {
            #pragma unroll
            for (int j = 0; j < 2; ++j) {
                const int chunk = w * 2 + j;
                const unsigned short* src = fbase
                    + ((size_t)((nt + 1) * 4 + (chunk >> 2)) * 4 + (chunk & 3)) * 512
                    + (size_t)l * 8;
                gload_lds16(src, &Fst[(nt + 1) & 1][chunk * 512]);
            }
        }
        bf16x8 ff[4];
        #pragma unroll
        for (int q = 0; q < 4; ++q)
            ff[q] = *(const bf16x8*)&Fst[nt & 1][(nsub * 4 + q) * 512 + l * 8];
        f32x16 s;
        #pragma unroll
        for (int r = 0; r < 16; ++r) s[r] = 0.f;
        #pragma unroll
        for (int q = 0; q < 4; ++q)
            s = __builtin_amdgcn_mfma_f32_32x32x16_bf16(ff[q], gfrag[q], s, 0, 0, 0);
        unsigned short* ew = &Ebuf[nt & 1][(mt * 32 + lane) * 136 + nsub * 32 + half * 4];
        #pragma unroll
        for (int r4 = 0; r4 < 4; ++r4) {
            float e0 = __expf(s[r4 * 4 + 0]);
            float e1 = __expf(s[r4 * 4 + 1]);
            float e2 = __expf(s[r4 * 4 + 2]);
            float e3 = __expf(s[r4 * 4 + 3]);
            denp += (e0 + e1) + (e2 + e3);
            uint2 pk;
            pk.x = cvt_pk_bf16(e0, e1);
            pk.y = cvt_pk_bf16(e2, e3);
            *(uint2*)(ew + r4 * 8) = pk;
        }
        bf16x8 hreg[8];
        {
            const unsigned short* hp = hbase + (size_t)(nt * 8) * 512;
            #pragma unroll
            for (int q = 0; q < 8; ++q)
                hreg[q] = *(const bf16x8*)(hp + (size_t)q * 512);
        }
        __syncthreads();
        const unsigned short* eb = &Ebuf[nt & 1][0];
        #pragma unroll
        for (int q = 0; q < 8; ++q) {
            bf16x8 b0 = *(const bf16x8*)(eb + lane * 136 + q * 16 + half * 8);
            bf16x8 b1 = *(const bf16x8*)(eb + (32 + lane) * 136 + q * 16 + half * 8);
            acc[0] = __builtin_amdgcn_mfma_f32_32x32x16_bf16(hreg[q], b0, acc[0], 0, 0, 0);
            acc[1] = __builtin_amdgcn_mfma_f32_32x32x16_bf16(hreg[q], b1, acc[1], 0, 0, 0);
        }
    }

    denp += __shfl_xor(denp, 32, 64);
    if (l < 32) den_part[nsub][mt * 32 + lane] = denp;
    __syncthreads();
    if (t < 64) {
        float d = den_part[0][t] + den_part[1][t] + den_part[2][t] + den_part[3][t];
        den_inv[t] = 1.0f / d;
    }
    __syncthreads();

    const float gs = gamma_p[0];
    #pragma unroll
    for (int mt2 = 0; mt2 < 2; ++mt2) {
        const int mloc = mt2 * 32 + lane;
        const float dinv = den_inv[mloc];
        const int m = m0 + mloc;
        #pragma unroll
        for (int r = 0; r < 16; ++r) {
            const int c = ctg * 32 + (r & 3) + ((r >> 2) * 8) + half * 4;
            const size_t idx = ((size_t)(b * C_IN + c)) * N_PIX + m;
            out[idx] = gs * acc[mt2][r] * dinv + x[idx];
        }
    }
}

// ---------------------------------------------------------------------------
extern "C" void kernel_launch(void* const* d_in, const int* in_sizes, int n_in,
                              void* d_out, int out_size, void* d_ws, size_t ws_size,
                              hipStream_t stream)
{
    const float* x     = (const float*)d_in[0];
    const float* f_w   = (const float*)d_in[1];
    const float* f_b   = (const float*)d_in[2];
    const float* g_w   = (const float*)d_in[3];
    const float* g_b   = (const float*)d_in[4];
    const float* h_w   = (const float*)d_in[5];
    const float* h_b   = (const float*)d_in[6];
    const float* gamma = (const float*)d_in[7];
    float* out = (float*)d_out;

    unsigned short* fa   = (unsigned short*)d_ws;        // 1M shorts (2 MB)
    unsigned short* gbuf = fa + (1u << 20);              // 1M shorts
    unsigned short* ha   = gbuf + (1u << 20);            // 8M shorts (16 MB)
    unsigned short* wfg  = ha + (8u << 20);              // 64K shorts
    unsigned short* whb  = wfg + (1u << 16);             // 256K shorts (contiguous wall)

    pack_w<<<160, 256, 0, stream>>>(f_w, g_w, h_w, wfg, whb);

    dim3 gp(64, 4);
    proj_fused<<<gp, 512, 0, stream>>>(x, wfg, f_b, g_b, h_b, fa, gbuf, ha);

    attn_kernel<<<512, 512, 0, stream>>>(fa, gbuf, ha, x, gamma, out);
}